// Round 2
// baseline (949.630 us; speedup 1.0000x reference)
//
#include <hip/hip_runtime.h>

// Problem dims (fixed by reference)
#define BB 32
#define HH 3
#define MM 2048
#define DD 512
#define LL 32
#define TT 2049
#define NCHUNK 32            // m-chunks for weighted partials
#define MCHUNK (MM / NCHUNK) // 64 m per block
#define NT2 16               // t-chunks for TC matvec partials
#define TCH 129              // ceil(TT / NT2)

// ---------------------------------------------------------------------------
// k1: u[b,d] = sum_l B_emb[query[b,l], d] * pos_enc[l, d]
// ---------------------------------------------------------------------------
__global__ __launch_bounds__(256) void qembed_kernel(
    const int* __restrict__ query, const float* __restrict__ B_emb,
    const float* __restrict__ pos_enc, float* __restrict__ u) {
    int b = blockIdx.x;
    int d0 = threadIdx.x * 2;
    float a0 = 0.f, a1 = 0.f;
#pragma unroll 4
    for (int l = 0; l < LL; ++l) {
        int q = query[b * LL + l];
        float2 e = *(const float2*)(B_emb + (size_t)q * DD + d0);
        float2 pe = *(const float2*)(pos_enc + l * DD + d0);
        a0 += e.x * pe.x;
        a1 += e.y * pe.y;
    }
    u[b * DD + d0] = a0;
    u[b * DD + d0 + 1] = a1;
}

// ---------------------------------------------------------------------------
// k2: ta_dot[b,t] = dot(TA[hop,t,:], u[b,:])  — removes the 2KB TA gather
// from the streaming pass. grid: (ceil(T/4), BB) x 256 thr; one wave per t.
// TA read 32x (once per b) from L2/L3 (4.2 MB table).
// ---------------------------------------------------------------------------
__global__ __launch_bounds__(256) void tdot_kernel(
    const float* __restrict__ TA, const float* __restrict__ u,
    float* __restrict__ ta_dot, int hop) {
    int b = blockIdx.y;
    int wave = threadIdx.x >> 6, lane = threadIdx.x & 63;
    int t = blockIdx.x * 4 + wave;
    if (t >= TT) return;
    int d0 = lane * 8;
    const float* arow = TA + (size_t)(hop * TT + t) * DD + d0;
    const float* urow = u + b * DD + d0;
    float4 a0 = *(const float4*)arow;
    float4 a1 = *(const float4*)(arow + 4);
    float4 u0 = *(const float4*)urow;
    float4 u1 = *(const float4*)(urow + 4);
    float acc = a0.x * u0.x + a0.y * u0.y + a0.z * u0.z + a0.w * u0.w +
                a1.x * u1.x + a1.y * u1.y + a1.z * u1.z + a1.w * u1.w;
#pragma unroll
    for (int off = 32; off > 0; off >>= 1) acc += __shfl_xor(acc, off);
    if (lane == 0) ta_dot[b * TT + t] = acc;
}

// ---------------------------------------------------------------------------
// k3: logits[b,m] = dot(key_mems[b,hop,m,:], u[b,:]) + ta_dot[b, rel_time[b,m]]
// Pure sequential stream of key_mems (128 MB/hop). grid: (MM/16, BB) x 256;
// wave handles 4 m-rows. No gathers (t lookup is a 4B L2 hit).
// ---------------------------------------------------------------------------
__global__ __launch_bounds__(256) void logits_kernel(
    const float* __restrict__ key_mems, const int* __restrict__ rel_time,
    const float* __restrict__ u, const float* __restrict__ ta_dot,
    float* __restrict__ logits, int hop) {
    int b = blockIdx.y;
    int wave = threadIdx.x >> 6, lane = threadIdx.x & 63;
    int d0 = lane * 8;
    float4 u0 = *(const float4*)(u + b * DD + d0);
    float4 u1 = *(const float4*)(u + b * DD + d0 + 4);
    const size_t kbase = (size_t)(b * HH + hop) * MM * DD;
#pragma unroll
    for (int j = 0; j < 4; ++j) {
        int m = blockIdx.x * 16 + wave * 4 + j;
        const float* krow = key_mems + kbase + (size_t)m * DD + d0;
        float4 k0 = *(const float4*)krow;
        float4 k1 = *(const float4*)(krow + 4);
        float acc = k0.x * u0.x + k0.y * u0.y + k0.z * u0.z + k0.w * u0.w +
                    k1.x * u1.x + k1.y * u1.y + k1.z * u1.z + k1.w * u1.w;
#pragma unroll
        for (int off = 32; off > 0; off >>= 1) acc += __shfl_xor(acc, off);
        if (lane == 0)
            logits[b * MM + m] = acc + ta_dot[b * TT + rel_time[b * MM + m]];
    }
}

// ---------------------------------------------------------------------------
// k4: softmax over M per batch row (in place) + bin p into w[b,t] via LDS
// atomics: w[t] = sum_{m: rel_time[b,m]=t} p[b,m]. grid: BB x 256.
// ---------------------------------------------------------------------------
__global__ __launch_bounds__(256) void softmax_bins_kernel(
    float* __restrict__ logits, const int* __restrict__ rel_time,
    float* __restrict__ wbin) {
    __shared__ float bins[TT];
    __shared__ float smx[4];
    __shared__ float ssm[4];
    int b = blockIdx.x;
    int tid = threadIdx.x;
    int wave = tid >> 6, lane = tid & 63;
    float* row = logits + b * MM;

    for (int i = tid; i < TT; i += 256) bins[i] = 0.f;

    float vals[8];
    float mx = -3.4e38f;
#pragma unroll
    for (int j = 0; j < 8; ++j) {
        vals[j] = row[j * 256 + tid];
        mx = fmaxf(mx, vals[j]);
    }
#pragma unroll
    for (int off = 32; off > 0; off >>= 1) mx = fmaxf(mx, __shfl_xor(mx, off));
    if (lane == 0) smx[wave] = mx;
    __syncthreads();
    mx = fmaxf(fmaxf(smx[0], smx[1]), fmaxf(smx[2], smx[3]));

    float s = 0.f;
#pragma unroll
    for (int j = 0; j < 8; ++j) {
        vals[j] = expf(vals[j] - mx);
        s += vals[j];
    }
#pragma unroll
    for (int off = 32; off > 0; off >>= 1) s += __shfl_xor(s, off);
    if (lane == 0) ssm[wave] = s;
    __syncthreads();
    s = (ssm[0] + ssm[1]) + (ssm[2] + ssm[3]);
    float inv = 1.f / s;
#pragma unroll
    for (int j = 0; j < 8; ++j) {
        float pv = vals[j] * inv;
        row[j * 256 + tid] = pv;
        int t = rel_time[b * MM + j * 256 + tid];
        atomicAdd(&bins[t], pv);
    }
    __syncthreads();
    for (int i = tid; i < TT; i += 256) wbin[b * TT + i] = bins[i];
}

// ---------------------------------------------------------------------------
// k5: partials[c,b,d] = sum_{m in chunk c} val_mems[b,hop,m,d] * p[b,m]
// Pure sequential stream of val_mems (128 MB/hop), no TC gather.
// grid: (NCHUNK, BB) x 256 = 4 waves; wave w owns m = base+4j+w.
// ---------------------------------------------------------------------------
__global__ __launch_bounds__(256) void weighted_kernel(
    const float* __restrict__ val_mems, const float* __restrict__ p,
    float* __restrict__ partials, int hop) {
    __shared__ float sm[4][DD];
    int b = blockIdx.y, c = blockIdx.x;
    int wave = threadIdx.x >> 6, lane = threadIdx.x & 63;
    int d0 = lane * 8;
    const size_t vbase = (size_t)(b * HH + hop) * MM * DD;

    float acc[8] = {0.f, 0.f, 0.f, 0.f, 0.f, 0.f, 0.f, 0.f};
#pragma unroll 2
    for (int j = 0; j < MCHUNK / 4; ++j) {
        int m = c * MCHUNK + j * 4 + wave;
        float pw = p[b * MM + m];
        const float* vrow = val_mems + vbase + (size_t)m * DD + d0;
        float4 v0 = *(const float4*)vrow;
        float4 v1 = *(const float4*)(vrow + 4);
        acc[0] += v0.x * pw;
        acc[1] += v0.y * pw;
        acc[2] += v0.z * pw;
        acc[3] += v0.w * pw;
        acc[4] += v1.x * pw;
        acc[5] += v1.y * pw;
        acc[6] += v1.z * pw;
        acc[7] += v1.w * pw;
    }
#pragma unroll
    for (int k = 0; k < 8; ++k) sm[wave][d0 + k] = acc[k];
    __syncthreads();
#pragma unroll
    for (int r = 0; r < 2; ++r) {
        int d = threadIdx.x * 2 + r;
        float v = (sm[0][d] + sm[1][d]) + (sm[2][d] + sm[3][d]);
        partials[((size_t)c * BB + b) * DD + d] = v;
    }
}

// ---------------------------------------------------------------------------
// k6: partials2[tc,b,d] = sum_{t in t-chunk} wbin[b,t] * TC[hop,t,d]
// [B,T]x[T,D] matvec; TC rows read coalesced, block-uniform skip of w==0.
// grid: (NT2, BB) x 256 threads (2 d each).
// ---------------------------------------------------------------------------
__global__ __launch_bounds__(256) void tc_kernel(
    const float* __restrict__ TC, const float* __restrict__ wbin,
    float* __restrict__ partials2, int hop) {
    __shared__ float wl[TCH];
    int b = blockIdx.y, tc = blockIdx.x;
    int t0 = tc * TCH;
    int tid = threadIdx.x;
    for (int i = tid; i < TCH; i += 256) {
        int t = t0 + i;
        wl[i] = (t < TT) ? wbin[b * TT + t] : 0.f;
    }
    __syncthreads();
    int d = tid * 2;
    float ax = 0.f, ay = 0.f;
    for (int i = 0; i < TCH; ++i) {
        int t = t0 + i;
        if (t >= TT) break;
        float wv = wl[i];
        if (wv != 0.f) {  // block-uniform branch (wl[i] same for all threads)
            float2 tcv = *(const float2*)(TC + (size_t)(hop * TT + t) * DD + d);
            ax += wv * tcv.x;
            ay += wv * tcv.y;
        }
    }
    float2 o;
    o.x = ax;
    o.y = ay;
    *(float2*)(partials2 + ((size_t)tc * BB + b) * DD + d) = o;
}

// ---------------------------------------------------------------------------
// k7: u[idx] += sum_c partials[c,idx] + sum_tc partials2[tc,idx];
//     on last hop also writes out.
// ---------------------------------------------------------------------------
__global__ __launch_bounds__(256) void update_kernel(
    const float* __restrict__ partials, const float* __restrict__ partials2,
    float* __restrict__ u, float* __restrict__ out, int write_out) {
    int idx = blockIdx.x * 256 + threadIdx.x;
    float s = 0.f;
#pragma unroll
    for (int c = 0; c < NCHUNK; ++c) s += partials[(size_t)c * BB * DD + idx];
#pragma unroll
    for (int tc = 0; tc < NT2; ++tc)
        s += partials2[(size_t)tc * BB * DD + idx];
    float uu = u[idx] + s;
    u[idx] = uu;
    if (write_out) out[idx] = uu;
}

extern "C" void kernel_launch(void* const* d_in, const int* in_sizes, int n_in,
                              void* d_out, int out_size, void* d_ws, size_t ws_size,
                              hipStream_t stream) {
    const int* query = (const int*)d_in[0];
    const int* rel_time = (const int*)d_in[1];
    const float* key_mems = (const float*)d_in[2];
    const float* val_mems = (const float*)d_in[3];
    const float* B_emb = (const float*)d_in[4];
    const float* TA = (const float*)d_in[5];
    const float* TC = (const float*)d_in[6];
    const float* pos_enc = (const float*)d_in[7];
    float* out = (float*)d_out;

    float* ws = (float*)d_ws;
    float* u = ws;                                  // B*D        = 16384
    float* logits = u + BB * DD;                    // B*M        = 65536
    float* ta_dot = logits + BB * MM;               // B*T        = 65568
    float* wbin = ta_dot + BB * TT;                 // B*T        = 65568
    float* partials = wbin + BB * TT;               // NCHUNK*B*D = 524288
    float* partials2 = partials + NCHUNK * BB * DD; // NT2*B*D    = 262144

    qembed_kernel<<<BB, 256, 0, stream>>>(query, B_emb, pos_enc, u);

    for (int hop = 0; hop < HH; ++hop) {
        tdot_kernel<<<dim3((TT + 3) / 4, BB), 256, 0, stream>>>(
            TA, u, ta_dot, hop);
        logits_kernel<<<dim3(MM / 16, BB), 256, 0, stream>>>(
            key_mems, rel_time, u, ta_dot, logits, hop);
        softmax_bins_kernel<<<BB, 256, 0, stream>>>(logits, rel_time, wbin);
        weighted_kernel<<<dim3(NCHUNK, BB), 256, 0, stream>>>(
            val_mems, logits, partials, hop);
        tc_kernel<<<dim3(NT2, BB), 256, 0, stream>>>(TC, wbin, partials2, hop);
        update_kernel<<<BB * DD / 256, 256, 0, stream>>>(
            partials, partials2, u, out, hop == HH - 1 ? 1 : 0);
    }
}